// Round 1
// baseline (631.423 us; speedup 1.0000x reference)
//
#include <hip/hip_runtime.h>
#include <math.h>

#define NT 16384     // tokens
#define NE 4096      // embed
#define NX 64        // experts
#define TK 8         // top-k

// GEMM tiling
#define BM 64
#define BN 128       // 64 route cols | 64 noise cols
#define BK 32
#define TM 8
#define TN 4
#define XPITCH (BM + 4)   // 68: keeps 16B alignment for float4 LDS reads, spreads banks

#define RO_SIZE (NT * NX)            // 1048576 router_output floats
#define TI_OFF  RO_SIZE              // top_idx (as float) offset
#define AUX_IDX (RO_SIZE + NT * TK)  // 1179648 aux_loss scalar

#define MAXFLAG 4096
#define DELTA 5e-5f   // min adjacent top-value gap below which we fp64-refine

__device__ __forceinline__ float neginf() { return __int_as_float(0xff800000); }

// ---------------------------------------------------------------------------
// Fused: dual GEMM (fp32 VALU) + per-token routing epilogue
// grid = NT/BM = 256 blocks, 256 threads
// ---------------------------------------------------------------------------
__global__ __launch_bounds__(256) void fused_router_kernel(
    const float* __restrict__ x,
    const float* __restrict__ w_route,
    const float* __restrict__ b_route,
    const float* __restrict__ w_noise,
    const float* __restrict__ b_noise,
    const float* __restrict__ noise,
    float* __restrict__ out,
    float* __restrict__ ps_acc,   // [64] sum of softmax probs
    float* __restrict__ fr_acc,   // [64] freq counts (float)
    float* __restrict__ lse2_acc, // [1]  sum of lse^2
    int* __restrict__ flag_cnt,
    int* __restrict__ flag_list)
{
    __shared__ float smem[BM * BN];       // 8192 floats = 32 KB (reused for epilogue)
    float* xs  = smem;                     // [BK][XPITCH] transposed x tile
    float* wst = smem + BK * XPITCH;       // [BK][BN] combined weight tile

    const int tid = threadIdx.x;
    const int block_m = blockIdx.x * BM;
    const int row0 = (tid >> 5) * TM;      // 0..56
    const int col0 = (tid & 31) * TN;      // 0..124

    float acc[TM][TN];
    #pragma unroll
    for (int i = 0; i < TM; ++i)
        #pragma unroll
        for (int j = 0; j < TN; ++j) acc[i][j] = 0.f;

    float4 px[2], pw[4];

    // prefetch tile 0 into registers
    {
        #pragma unroll
        for (int s = 0; s < 2; ++s) {
            int f = tid + s * 256, r = f >> 3, kq = f & 7;
            px[s] = *reinterpret_cast<const float4*>(
                x + (size_t)(block_m + r) * NE + kq * 4);
        }
        #pragma unroll
        for (int s = 0; s < 4; ++s) {
            int f = tid + s * 256, kk = f >> 5, c4 = (f & 31) * 4;
            const float* src = (c4 < NX)
                ? (w_route + (size_t)kk * NX + c4)
                : (w_noise + (size_t)kk * NX + (c4 - NX));
            pw[s] = *reinterpret_cast<const float4*>(src);
        }
    }

    for (int t = 0; t < NE / BK; ++t) {
        __syncthreads();   // previous tile's compute done
        // staged regs -> LDS (x transposed)
        #pragma unroll
        for (int s = 0; s < 2; ++s) {
            int f = tid + s * 256, r = f >> 3, kq = f & 7;
            xs[(kq * 4 + 0) * XPITCH + r] = px[s].x;
            xs[(kq * 4 + 1) * XPITCH + r] = px[s].y;
            xs[(kq * 4 + 2) * XPITCH + r] = px[s].z;
            xs[(kq * 4 + 3) * XPITCH + r] = px[s].w;
        }
        #pragma unroll
        for (int s = 0; s < 4; ++s) {
            int f = tid + s * 256, kk = f >> 5, c4 = (f & 31) * 4;
            *reinterpret_cast<float4*>(&wst[kk * BN + c4]) = pw[s];
        }
        __syncthreads();
        // issue next tile's global loads early (hide HBM latency under FMAs)
        if (t + 1 < NE / BK) {
            const int k0 = (t + 1) * BK;
            #pragma unroll
            for (int s = 0; s < 2; ++s) {
                int f = tid + s * 256, r = f >> 3, kq = f & 7;
                px[s] = *reinterpret_cast<const float4*>(
                    x + (size_t)(block_m + r) * NE + k0 + kq * 4);
            }
            #pragma unroll
            for (int s = 0; s < 4; ++s) {
                int f = tid + s * 256, kk = f >> 5, c4 = (f & 31) * 4;
                const float* src = (c4 < NX)
                    ? (w_route + (size_t)(k0 + kk) * NX + c4)
                    : (w_noise + (size_t)(k0 + kk) * NX + (c4 - NX));
                pw[s] = *reinterpret_cast<const float4*>(src);
            }
        }
        // compute tile t
        #pragma unroll
        for (int k = 0; k < BK; ++k) {
            float4 xa = *reinterpret_cast<const float4*>(&xs[k * XPITCH + row0]);
            float4 xb = *reinterpret_cast<const float4*>(&xs[k * XPITCH + row0 + 4]);
            float4 wv = *reinterpret_cast<const float4*>(&wst[k * BN + col0]);
            float xf[TM] = {xa.x, xa.y, xa.z, xa.w, xb.x, xb.y, xb.z, xb.w};
            float wf[TN] = {wv.x, wv.y, wv.z, wv.w};
            #pragma unroll
            for (int i = 0; i < TM; ++i)
                #pragma unroll
                for (int j = 0; j < TN; ++j)
                    acc[i][j] = fmaf(xf[i], wf[j], acc[i][j]);
        }
    }

    // ---- epilogue: logits -> LDS, then per-token routing (wave = 64 lanes) ----
    __syncthreads();
    #pragma unroll
    for (int i = 0; i < TM; ++i) {
        float4 v = make_float4(acc[i][0], acc[i][1], acc[i][2], acc[i][3]);
        *reinterpret_cast<float4*>(&smem[(row0 + i) * BN + col0]) = v;
    }
    __syncthreads();

    const int wave = tid >> 6;
    const int lane = tid & 63;
    const float br = b_route[lane];
    const float bn = b_noise[lane];
    float ps_l = 0.f, fr_l = 0.f, l2_l = 0.f;

    for (int tt = 0; tt < BM / 4; ++tt) {
        const int tok = wave * (BM / 4) + tt;
        const int gt  = block_m + tok;
        float lr = smem[tok * BN + lane] + br;
        float ln = smem[tok * BN + NX + lane] + bn;
        float nz = noise[(size_t)gt * NX + lane];
        float sp = fmaxf(ln, 0.f) + log1pf(expf(-fabsf(ln)));   // softplus
        float v  = lr + nz * sp;                                 // noisy logit

        // top-9 by iterative wave argmax (ties -> lower index, matches lax.top_k)
        float vv = v;
        float tv[9]; int ti[9];
        #pragma unroll
        for (int s = 0; s < 9; ++s) {
            float mv = vv; int mi = lane;
            #pragma unroll
            for (int off = 32; off > 0; off >>= 1) {
                float ov = __shfl_xor(mv, off);
                int   oi = __shfl_xor(mi, off);
                if (ov > mv || (ov == mv && oi < mi)) { mv = ov; mi = oi; }
            }
            tv[s] = mv; ti[s] = mi;
            if (lane == mi) vv = neginf();
        }

        // flag near-ties for fp64 refinement
        float ming = 1e30f;
        #pragma unroll
        for (int s = 0; s < 8; ++s) ming = fminf(ming, tv[s] - tv[s + 1]);
        if (lane == 0 && ming < DELTA) {
            int p = atomicAdd(flag_cnt, 1);
            if (p < MAXFLAG) flag_list[p] = gt;
        }

        // sparse softmax over top-8
        const float m0 = tv[0];
        float e8[8], s8 = 0.f;
        #pragma unroll
        for (int s = 0; s < 8; ++s) { e8[s] = expf(tv[s] - m0); s8 += e8[s]; }
        float r = 0.f;
        #pragma unroll
        for (int s = 0; s < 8; ++s) if (ti[s] == lane) r = e8[s] / s8;
        out[(size_t)gt * NX + lane] = r;
        if (lane < TK) out[TI_OFF + (size_t)gt * TK + lane] = (float)ti[lane];

        // dense softmax + logsumexp for aux loss
        float p = expf(v - m0);
        float s64 = p;
        #pragma unroll
        for (int off = 32; off > 0; off >>= 1) s64 += __shfl_xor(s64, off);
        ps_l += p / s64;
        if (lane == 0) { float lse = m0 + logf(s64); l2_l += lse * lse; }

        // freq (faithful torch scatter: gate>0 iff column-expert j is in top set)
        unsigned tm8 = 0;
        #pragma unroll
        for (int s = 0; s < 8; ++s) if (ti[s] < TK) tm8 |= (1u << ti[s]);
        #pragma unroll
        for (int s = 0; s < 8; ++s)
            if (ti[s] == lane && ((tm8 >> s) & 1u)) fr_l += 1.f;
    }
    atomicAdd(&ps_acc[lane], ps_l);
    atomicAdd(&fr_acc[lane], fr_l);
    if (lane == 0) atomicAdd(lse2_acc, l2_l);
}

// ---------------------------------------------------------------------------
// fp64 repair of near-tie tokens (router_output row + top_idx row only)
// ---------------------------------------------------------------------------
__global__ __launch_bounds__(64) void refine_kernel(
    const float* __restrict__ x, const float* __restrict__ w_route,
    const float* __restrict__ b_route, const float* __restrict__ w_noise,
    const float* __restrict__ b_noise, const float* __restrict__ noise,
    float* __restrict__ out, const int* __restrict__ flag_cnt,
    const int* __restrict__ flag_list)
{
    const int lane = threadIdx.x;
    int nf = *flag_cnt; if (nf > MAXFLAG) nf = MAXFLAG;
    for (int fi = blockIdx.x; fi < nf; fi += gridDim.x) {
        const int gt = flag_list[fi];
        const float* xr = x + (size_t)gt * NE;
        double a0=0,a1=0,a2=0,a3=0, c0=0,c1=0,c2=0,c3=0;
        for (int k = 0; k < NE; k += 4) {
            double x0 = xr[k], x1 = xr[k+1], x2 = xr[k+2], x3 = xr[k+3];
            a0 += x0 * (double)w_route[(size_t)(k    ) * NX + lane];
            a1 += x1 * (double)w_route[(size_t)(k + 1) * NX + lane];
            a2 += x2 * (double)w_route[(size_t)(k + 2) * NX + lane];
            a3 += x3 * (double)w_route[(size_t)(k + 3) * NX + lane];
            c0 += x0 * (double)w_noise[(size_t)(k    ) * NX + lane];
            c1 += x1 * (double)w_noise[(size_t)(k + 1) * NX + lane];
            c2 += x2 * (double)w_noise[(size_t)(k + 2) * NX + lane];
            c3 += x3 * (double)w_noise[(size_t)(k + 3) * NX + lane];
        }
        double lr = (a0 + a1) + (a2 + a3) + (double)b_route[lane];
        double ln = (c0 + c1) + (c2 + c3) + (double)b_noise[lane];
        double nz = (double)noise[(size_t)gt * NX + lane];
        double sp = (ln > 0.0) ? (ln + log1p(exp(-ln))) : log1p(exp(ln));
        double v  = lr + nz * sp;

        double vv = v;
        double tv[8]; int ti[8];
        #pragma unroll
        for (int s = 0; s < 8; ++s) {
            double mv = vv; int mi = lane;
            #pragma unroll
            for (int off = 32; off > 0; off >>= 1) {
                double ov = __shfl_xor(mv, off);
                int    oi = __shfl_xor(mi, off);
                if (ov > mv || (ov == mv && oi < mi)) { mv = ov; mi = oi; }
            }
            tv[s] = mv; ti[s] = mi;
            if (lane == mi) vv = -1.0e300;
        }
        double m0 = tv[0], s8 = 0.0, e8[8];
        #pragma unroll
        for (int s = 0; s < 8; ++s) { e8[s] = exp(tv[s] - m0); s8 += e8[s]; }
        float r = 0.f;
        #pragma unroll
        for (int s = 0; s < 8; ++s) if (ti[s] == lane) r = (float)(e8[s] / s8);
        out[(size_t)gt * NX + lane] = r;
        if (lane < TK) out[TI_OFF + (size_t)gt * TK + lane] = (float)ti[lane];
    }
}

// ---------------------------------------------------------------------------
// aux loss finalize (1 wave)
// ---------------------------------------------------------------------------
__global__ __launch_bounds__(64) void finalize_kernel(
    const float* __restrict__ ps_acc, const float* __restrict__ fr_acc,
    const float* __restrict__ lse2_acc, float* __restrict__ out)
{
    const int lane = threadIdx.x;
    float p = ps_acc[lane], f = fr_acc[lane];
    float sp = p, sf = f;
    #pragma unroll
    for (int off = 32; off > 0; off >>= 1) {
        sp += __shfl_xor(sp, off);
        sf += __shfl_xor(sf, off);
    }
    float d = (p / fmaxf(sp, 1e-12f)) * (f / fmaxf(sf, 1e-12f));
    #pragma unroll
    for (int off = 32; off > 0; off >>= 1) d += __shfl_xor(d, off);
    if (lane == 0)
        out[AUX_IDX] = 64.f * d + 0.1f * (lse2_acc[0] / (float)NT);
}

// ---------------------------------------------------------------------------
extern "C" void kernel_launch(void* const* d_in, const int* in_sizes, int n_in,
                              void* d_out, int out_size, void* d_ws, size_t ws_size,
                              hipStream_t stream) {
    const float* x       = (const float*)d_in[0];
    const float* w_route = (const float*)d_in[1];
    const float* b_route = (const float*)d_in[2];
    const float* w_noise = (const float*)d_in[3];
    const float* b_noise = (const float*)d_in[4];
    const float* noise   = (const float*)d_in[5];
    float* out = (float*)d_out;

    float* ps   = (float*)d_ws;          // [64]
    float* fr   = ps + 64;               // [64]
    float* lse2 = ps + 128;              // [1]
    int* flag_cnt  = (int*)(ps + 129);   // [1]
    int* flag_list = (int*)(ps + 130);   // [MAXFLAG]

    hipMemsetAsync(d_ws, 0, (size_t)(130 + MAXFLAG) * sizeof(float), stream);

    fused_router_kernel<<<NT / BM, 256, 0, stream>>>(
        x, w_route, b_route, w_noise, b_noise, noise, out,
        ps, fr, lse2, flag_cnt, flag_list);

    refine_kernel<<<128, 64, 0, stream>>>(
        x, w_route, b_route, w_noise, b_noise, noise, out, flag_cnt, flag_list);

    finalize_kernel<<<1, 64, 0, stream>>>(ps, fr, lse2, out);
}

// Round 2
// 320.291 us; speedup vs baseline: 1.9714x; 1.9714x over previous
//
#include <hip/hip_runtime.h>
#include <math.h>

#define NT 16384     // tokens
#define NE 4096      // embed
#define NX 64        // experts
#define TK 8         // top-k

#define BM 64
#define BN 128
#define BK 32
#define KT (NE / BK)   // 128 k-tiles

#define RO_SIZE (NT * NX)
#define TI_OFF  RO_SIZE
#define AUX_IDX (RO_SIZE + NT * TK)

#define MAXFLAG 8192
#define STATS_FLOATS (130 + MAXFLAG)
#define WPACK_OFF ((((STATS_FLOATS * 4) + 63) / 64) * 64)  // byte offset of wt_hi in ws
#define WMAT_ELEMS (128 * NE)                              // 524288 bf16 per matrix
#define WS_NEED ((size_t)WPACK_OFF + 2 * (size_t)WMAT_ELEMS * 2)

#define DELTA_FP32 5e-5f    // fallback path (fp32 GEMM)
#define DELTA_BF16 2.5e-4f  // bf16x3 path (sigma ~1.5e-5, 17-sigma margin)

typedef __attribute__((ext_vector_type(8))) short bf16x8_t;
typedef __attribute__((ext_vector_type(4))) float f32x4_t;

__device__ __forceinline__ float neginf() { return __int_as_float(0xff800000); }

__device__ __forceinline__ unsigned short bf16_trunc(float f) {
    return (unsigned short)(__float_as_uint(f) >> 16);
}
__device__ __forceinline__ unsigned short bf16_rtn(float f) {
    unsigned u = __float_as_uint(f);
    unsigned r = u + 0x7fffu + ((u >> 16) & 1u);
    return (unsigned short)(r >> 16);
}
__device__ __forceinline__ float bf16_to_f(unsigned short h) {
    return __uint_as_float(((unsigned)h) << 16);
}

// ---------------------------------------------------------------------------
// prep: w_route|w_noise fp32 [4096][64] -> wt_hi/wt_lo bf16 [128 cols][4096 k]
// (transposed so main kernel loads 8 contiguous k per lane fragment)
// ---------------------------------------------------------------------------
__global__ __launch_bounds__(256) void prep_w_kernel(
    const float* __restrict__ w_route, const float* __restrict__ w_noise,
    unsigned short* __restrict__ wt_hi, unsigned short* __restrict__ wt_lo)
{
    __shared__ unsigned short hi[128][64];  // 16 KB
    __shared__ unsigned short lo[128][64];  // 16 KB
    const int t = threadIdx.x;
    const int k0 = blockIdx.x * 64;

    #pragma unroll
    for (int s = 0; s < 4; ++s) {
        int f = t + s * 256;          // 0..1023 float4 slots (64 k-rows x 16 col-quads)
        int kr = f >> 4;              // 0..63
        int e4 = (f & 15) * 4;        // 0..60
        float4 vr = *(const float4*)(w_route + (size_t)(k0 + kr) * NX + e4);
        float4 vn = *(const float4*)(w_noise + (size_t)(k0 + kr) * NX + e4);
        float ar[4] = {vr.x, vr.y, vr.z, vr.w};
        float an[4] = {vn.x, vn.y, vn.z, vn.w};
        #pragma unroll
        for (int j = 0; j < 4; ++j) {
            unsigned short h = bf16_trunc(ar[j]);
            hi[e4 + j][kr] = h;
            lo[e4 + j][kr] = bf16_rtn(ar[j] - bf16_to_f(h));
            h = bf16_trunc(an[j]);
            hi[64 + e4 + j][kr] = h;
            lo[64 + e4 + j][kr] = bf16_rtn(an[j] - bf16_to_f(h));
        }
    }
    __syncthreads();
    #pragma unroll
    for (int s = 0; s < 4; ++s) {
        int c = t + s * 256;          // 0..1023 16B chunks
        int col = c >> 3;
        int ks = (c & 7) * 8;
        *(bf16x8_t*)(wt_hi + (size_t)col * NE + k0 + ks) = *(bf16x8_t*)&hi[col][ks];
        *(bf16x8_t*)(wt_lo + (size_t)col * NE + k0 + ks) = *(bf16x8_t*)&lo[col][ks];
    }
}

// ---------------------------------------------------------------------------
// Main fused kernel: bf16x3 MFMA dual-GEMM + routing epilogue
// grid = 256 blocks x 256 threads (4 waves, 2x2 over 64x128 tile)
// ---------------------------------------------------------------------------
__global__ __launch_bounds__(256) void fused_router_mfma(
    const float* __restrict__ x,
    const unsigned short* __restrict__ wt_hi,
    const unsigned short* __restrict__ wt_lo,
    const float* __restrict__ b_route, const float* __restrict__ b_noise,
    const float* __restrict__ noise,
    float* __restrict__ out,
    float* __restrict__ ps_acc, float* __restrict__ fr_acc,
    float* __restrict__ lse2_acc,
    int* __restrict__ flag_cnt, int* __restrict__ flag_list)
{
    // per buffer (ushort units): A_hi[0..2047] A_lo[2048..4095] B_hi[4096..8191] B_lo[8192..12287]
    __shared__ __align__(16) unsigned short lds[2][12288];   // 48 KB

    const int tid = threadIdx.x;
    const int bm = blockIdx.x * BM;
    const int wid = tid >> 6;
    const int lane = tid & 63;
    const int l15 = lane & 15;
    const int kg = lane >> 4;            // k-group 0..3
    const int wr0 = (wid >> 1) * 32;     // wave row origin (0 or 32)
    const int wc0 = (wid & 1) * 64;      // wave col origin (0 or 64)

    // staging assignments
    const int arow = tid >> 2, asl = tid & 3;          // A: 64 rows x 4 slots
    const int bcol = tid >> 1, bs2 = (tid & 1) * 2;    // B: 128 cols x 2 slot-pairs

    f32x4_t acc[2][4];
    #pragma unroll
    for (int rf = 0; rf < 2; ++rf)
        #pragma unroll
        for (int cf = 0; cf < 4; ++cf)
            acc[rf][cf] = (f32x4_t){0.f, 0.f, 0.f, 0.f};

    float4 pa0, pa1;
    bf16x8_t pbh0, pbh1, pbl0, pbl1;

    // ---- tile register prefetch ----
    #define LOAD_TILE(TKI) do {                                                 \
        const int k0_ = (TKI) * BK;                                             \
        const float* xp_ = x + (size_t)(bm + arow) * NE + k0_ + asl * 8;        \
        pa0 = *(const float4*)xp_;                                              \
        pa1 = *(const float4*)(xp_ + 4);                                        \
        const unsigned short* bh_ = wt_hi + (size_t)bcol * NE + k0_ + bs2 * 8;  \
        const unsigned short* bl_ = wt_lo + (size_t)bcol * NE + k0_ + bs2 * 8;  \
        pbh0 = *(const bf16x8_t*)bh_;  pbh1 = *(const bf16x8_t*)(bh_ + 8);      \
        pbl0 = *(const bf16x8_t*)bl_;  pbl1 = *(const bf16x8_t*)(bl_ + 8);      \
    } while (0)

    #define WRITE_TILE(BUF) do {                                                \
        float af_[8] = {pa0.x, pa0.y, pa0.z, pa0.w, pa1.x, pa1.y, pa1.z, pa1.w};\
        bf16x8_t hv_, lv_;                                                      \
        _Pragma("unroll")                                                       \
        for (int j = 0; j < 8; ++j) {                                           \
            unsigned short h_ = bf16_trunc(af_[j]);                             \
            hv_[j] = (short)h_;                                                 \
            lv_[j] = (short)bf16_rtn(af_[j] - bf16_to_f(h_));                   \
        }                                                                       \
        int pa_ = asl ^ ((arow >> 1) & 3);                                      \
        *(bf16x8_t*)&lds[BUF][arow * 32 + pa_ * 8]        = hv_;                \
        *(bf16x8_t*)&lds[BUF][2048 + arow * 32 + pa_ * 8] = lv_;                \
        int p0_ = bs2 ^ ((bcol >> 1) & 3);                                      \
        int p1_ = (bs2 + 1) ^ ((bcol >> 1) & 3);                                \
        *(bf16x8_t*)&lds[BUF][4096 + bcol * 32 + p0_ * 8] = pbh0;               \
        *(bf16x8_t*)&lds[BUF][4096 + bcol * 32 + p1_ * 8] = pbh1;               \
        *(bf16x8_t*)&lds[BUF][8192 + bcol * 32 + p0_ * 8] = pbl0;               \
        *(bf16x8_t*)&lds[BUF][8192 + bcol * 32 + p1_ * 8] = pbl1;               \
    } while (0)

    LOAD_TILE(0);
    WRITE_TILE(0);
    __syncthreads();

    for (int tk = 0; tk < KT; ++tk) {
        const int cur = tk & 1;
        if (tk + 1 < KT) LOAD_TILE(tk + 1);

        // compute from lds[cur]
        {
            const unsigned short* Ah = &lds[cur][0];
            const unsigned short* Al = &lds[cur][2048];
            const unsigned short* Bh = &lds[cur][4096];
            const unsigned short* Bl = &lds[cur][8192];
            bf16x8_t ah[2], al[2], bh[4], bl[4];
            #pragma unroll
            for (int rf = 0; rf < 2; ++rf) {
                int row = wr0 + rf * 16 + l15;
                int off = row * 32 + ((kg ^ ((row >> 1) & 3)) << 3);
                ah[rf] = *(const bf16x8_t*)(Ah + off);
                al[rf] = *(const bf16x8_t*)(Al + off);
            }
            #pragma unroll
            for (int cf = 0; cf < 4; ++cf) {
                int col = wc0 + cf * 16 + l15;
                int off = col * 32 + ((kg ^ ((col >> 1) & 3)) << 3);
                bh[cf] = *(const bf16x8_t*)(Bh + off);
                bl[cf] = *(const bf16x8_t*)(Bl + off);
            }
            #pragma unroll
            for (int rf = 0; rf < 2; ++rf)
                #pragma unroll
                for (int cf = 0; cf < 4; ++cf) {
                    acc[rf][cf] = __builtin_amdgcn_mfma_f32_16x16x32_bf16(
                        ah[rf], bh[cf], acc[rf][cf], 0, 0, 0);
                    acc[rf][cf] = __builtin_amdgcn_mfma_f32_16x16x32_bf16(
                        ah[rf], bl[cf], acc[rf][cf], 0, 0, 0);
                    acc[rf][cf] = __builtin_amdgcn_mfma_f32_16x16x32_bf16(
                        al[rf], bh[cf], acc[rf][cf], 0, 0, 0);
                }
        }

        if (tk + 1 < KT) WRITE_TILE(cur ^ 1);
        __syncthreads();
    }

    // ---- write logits to LDS (reuse buffers) ----
    float* logits = (float*)&lds[0][0];   // 64*128*4 = 32 KB of the 48 KB
    #pragma unroll
    for (int rf = 0; rf < 2; ++rf)
        #pragma unroll
        for (int cf = 0; cf < 4; ++cf)
            #pragma unroll
            for (int j = 0; j < 4; ++j) {
                int row = wr0 + rf * 16 + (lane >> 4) * 4 + j;
                int col = wc0 + cf * 16 + l15;
                logits[row * BN + col] = acc[rf][cf][j];
            }
    __syncthreads();

    // ---- per-token routing epilogue (verified round 1) ----
    const float br = b_route[lane];
    const float bnv = b_noise[lane];
    float ps_l = 0.f, fr_l = 0.f, l2_l = 0.f;

    for (int tt = 0; tt < BM / 4; ++tt) {
        const int tok = wid * (BM / 4) + tt;
        const int gt  = bm + tok;
        float lr = logits[tok * BN + lane] + br;
        float ln = logits[tok * BN + NX + lane] + bnv;
        float nz = noise[(size_t)gt * NX + lane];
        float sp = fmaxf(ln, 0.f) + log1pf(expf(-fabsf(ln)));   // softplus
        float v  = lr + nz * sp;                                 // noisy logit

        // top-9 iterative wave argmax (ties -> lower index)
        float vv = v;
        float tv[9]; int ti[9];
        #pragma unroll
        for (int s = 0; s < 9; ++s) {
            float mv = vv; int mi = lane;
            #pragma unroll
            for (int off = 32; off > 0; off >>= 1) {
                float ov = __shfl_xor(mv, off);
                int   oi = __shfl_xor(mi, off);
                if (ov > mv || (ov == mv && oi < mi)) { mv = ov; mi = oi; }
            }
            tv[s] = mv; ti[s] = mi;
            if (lane == mi) vv = neginf();
        }

        // flag near-ties for fp64 refinement
        float ming = 1e30f;
        #pragma unroll
        for (int s = 0; s < 8; ++s) ming = fminf(ming, tv[s] - tv[s + 1]);
        if (lane == 0 && ming < DELTA_BF16) {
            int p = atomicAdd(flag_cnt, 1);
            if (p < MAXFLAG) flag_list[p] = gt;
        }

        // sparse softmax over top-8
        const float m0 = tv[0];
        float e8[8], s8 = 0.f;
        #pragma unroll
        for (int s = 0; s < 8; ++s) { e8[s] = expf(tv[s] - m0); s8 += e8[s]; }
        float r = 0.f;
        #pragma unroll
        for (int s = 0; s < 8; ++s) if (ti[s] == lane) r = e8[s] / s8;
        out[(size_t)gt * NX + lane] = r;
        if (lane < TK) out[TI_OFF + (size_t)gt * TK + lane] = (float)ti[lane];

        // dense softmax + logsumexp for aux loss
        float p = expf(v - m0);
        float s64 = p;
        #pragma unroll
        for (int off = 32; off > 0; off >>= 1) s64 += __shfl_xor(s64, off);
        ps_l += p / s64;
        if (lane == 0) { float lse = m0 + logf(s64); l2_l += lse * lse; }

        // freq (faithful torch scatter semantics)
        unsigned tm8 = 0;
        #pragma unroll
        for (int s = 0; s < 8; ++s) if (ti[s] < TK) tm8 |= (1u << ti[s]);
        #pragma unroll
        for (int s = 0; s < 8; ++s)
            if (ti[s] == lane && ((tm8 >> s) & 1u)) fr_l += 1.f;
    }
    atomicAdd(&ps_acc[lane], ps_l);
    atomicAdd(&fr_acc[lane], fr_l);
    if (lane == 0) atomicAdd(lse2_acc, l2_l);
}

// ---------------------------------------------------------------------------
// Fallback fp32-VALU kernel (round-1 verified) for small ws_size
// ---------------------------------------------------------------------------
#define XPITCH (BM + 4)
__global__ __launch_bounds__(256) void fused_router_kernel(
    const float* __restrict__ x,
    const float* __restrict__ w_route, const float* __restrict__ b_route,
    const float* __restrict__ w_noise, const float* __restrict__ b_noise,
    const float* __restrict__ noise,
    float* __restrict__ out,
    float* __restrict__ ps_acc, float* __restrict__ fr_acc,
    float* __restrict__ lse2_acc,
    int* __restrict__ flag_cnt, int* __restrict__ flag_list)
{
    __shared__ float smem[BM * BN];
    float* xs  = smem;
    float* wst = smem + BK * XPITCH;
    const int tid = threadIdx.x;
    const int block_m = blockIdx.x * BM;
    const int row0 = (tid >> 5) * 8;
    const int col0 = (tid & 31) * 4;
    float acc[8][4];
    #pragma unroll
    for (int i = 0; i < 8; ++i)
        #pragma unroll
        for (int j = 0; j < 4; ++j) acc[i][j] = 0.f;
    float4 px[2], pw[4];
    {
        #pragma unroll
        for (int s = 0; s < 2; ++s) {
            int f = tid + s * 256, r = f >> 3, kq = f & 7;
            px[s] = *reinterpret_cast<const float4*>(x + (size_t)(block_m + r) * NE + kq * 4);
        }
        #pragma unroll
        for (int s = 0; s < 4; ++s) {
            int f = tid + s * 256, kk = f >> 5, c4 = (f & 31) * 4;
            const float* src = (c4 < NX) ? (w_route + (size_t)kk * NX + c4)
                                         : (w_noise + (size_t)kk * NX + (c4 - NX));
            pw[s] = *reinterpret_cast<const float4*>(src);
        }
    }
    for (int t = 0; t < NE / BK; ++t) {
        __syncthreads();
        #pragma unroll
        for (int s = 0; s < 2; ++s) {
            int f = tid + s * 256, r = f >> 3, kq = f & 7;
            xs[(kq * 4 + 0) * XPITCH + r] = px[s].x;
            xs[(kq * 4 + 1) * XPITCH + r] = px[s].y;
            xs[(kq * 4 + 2) * XPITCH + r] = px[s].z;
            xs[(kq * 4 + 3) * XPITCH + r] = px[s].w;
        }
        #pragma unroll
        for (int s = 0; s < 4; ++s) {
            int f = tid + s * 256, kk = f >> 5, c4 = (f & 31) * 4;
            *reinterpret_cast<float4*>(&wst[kk * BN + c4]) = pw[s];
        }
        __syncthreads();
        if (t + 1 < NE / BK) {
            const int k0 = (t + 1) * BK;
            #pragma unroll
            for (int s = 0; s < 2; ++s) {
                int f = tid + s * 256, r = f >> 3, kq = f & 7;
                px[s] = *reinterpret_cast<const float4*>(x + (size_t)(block_m + r) * NE + k0 + kq * 4);
            }
            #pragma unroll
            for (int s = 0; s < 4; ++s) {
                int f = tid + s * 256, kk = f >> 5, c4 = (f & 31) * 4;
                const float* src = (c4 < NX) ? (w_route + (size_t)(k0 + kk) * NX + c4)
                                             : (w_noise + (size_t)(k0 + kk) * NX + (c4 - NX));
                pw[s] = *reinterpret_cast<const float4*>(src);
            }
        }
        #pragma unroll
        for (int k = 0; k < BK; ++k) {
            float4 xa = *reinterpret_cast<const float4*>(&xs[k * XPITCH + row0]);
            float4 xb = *reinterpret_cast<const float4*>(&xs[k * XPITCH + row0 + 4]);
            float4 wv = *reinterpret_cast<const float4*>(&wst[k * BN + col0]);
            float xf[8] = {xa.x, xa.y, xa.z, xa.w, xb.x, xb.y, xb.z, xb.w};
            float wf[4] = {wv.x, wv.y, wv.z, wv.w};
            #pragma unroll
            for (int i = 0; i < 8; ++i)
                #pragma unroll
                for (int j = 0; j < 4; ++j)
                    acc[i][j] = fmaf(xf[i], wf[j], acc[i][j]);
        }
    }
    __syncthreads();
    #pragma unroll
    for (int i = 0; i < 8; ++i) {
        float4 v = make_float4(acc[i][0], acc[i][1], acc[i][2], acc[i][3]);
        *reinterpret_cast<float4*>(&smem[(row0 + i) * BN + col0]) = v;
    }
    __syncthreads();
    const int wave = tid >> 6;
    const int lane = tid & 63;
    const float br = b_route[lane];
    const float bnv = b_noise[lane];
    float ps_l = 0.f, fr_l = 0.f, l2_l = 0.f;
    for (int tt = 0; tt < BM / 4; ++tt) {
        const int tok = wave * (BM / 4) + tt;
        const int gt  = block_m + tok;
        float lr = smem[tok * BN + lane] + br;
        float ln = smem[tok * BN + NX + lane] + bnv;
        float nz = noise[(size_t)gt * NX + lane];
        float sp = fmaxf(ln, 0.f) + log1pf(expf(-fabsf(ln)));
        float v  = lr + nz * sp;
        float vv = v;
        float tv[9]; int ti[9];
        #pragma unroll
        for (int s = 0; s < 9; ++s) {
            float mv = vv; int mi = lane;
            #pragma unroll
            for (int off = 32; off > 0; off >>= 1) {
                float ov = __shfl_xor(mv, off);
                int   oi = __shfl_xor(mi, off);
                if (ov > mv || (ov == mv && oi < mi)) { mv = ov; mi = oi; }
            }
            tv[s] = mv; ti[s] = mi;
            if (lane == mi) vv = neginf();
        }
        float ming = 1e30f;
        #pragma unroll
        for (int s = 0; s < 8; ++s) ming = fminf(ming, tv[s] - tv[s + 1]);
        if (lane == 0 && ming < DELTA_FP32) {
            int p = atomicAdd(flag_cnt, 1);
            if (p < MAXFLAG) flag_list[p] = gt;
        }
        const float m0 = tv[0];
        float e8[8], s8 = 0.f;
        #pragma unroll
        for (int s = 0; s < 8; ++s) { e8[s] = expf(tv[s] - m0); s8 += e8[s]; }
        float r = 0.f;
        #pragma unroll
        for (int s = 0; s < 8; ++s) if (ti[s] == lane) r = e8[s] / s8;
        out[(size_t)gt * NX + lane] = r;
        if (lane < TK) out[TI_OFF + (size_t)gt * TK + lane] = (float)ti[lane];
        float p = expf(v - m0);
        float s64 = p;
        #pragma unroll
        for (int off = 32; off > 0; off >>= 1) s64 += __shfl_xor(s64, off);
        ps_l += p / s64;
        if (lane == 0) { float lse = m0 + logf(s64); l2_l += lse * lse; }
        unsigned tm8 = 0;
        #pragma unroll
        for (int s = 0; s < 8; ++s) if (ti[s] < TK) tm8 |= (1u << ti[s]);
        #pragma unroll
        for (int s = 0; s < 8; ++s)
            if (ti[s] == lane && ((tm8 >> s) & 1u)) fr_l += 1.f;
    }
    atomicAdd(&ps_acc[lane], ps_l);
    atomicAdd(&fr_acc[lane], fr_l);
    if (lane == 0) atomicAdd(lse2_acc, l2_l);
}

// ---------------------------------------------------------------------------
// fp64 repair of near-tie tokens: 256 threads, k split across 4 waves
// ---------------------------------------------------------------------------
__global__ __launch_bounds__(256) void refine_kernel(
    const float* __restrict__ x, const float* __restrict__ w_route,
    const float* __restrict__ b_route, const float* __restrict__ w_noise,
    const float* __restrict__ b_noise, const float* __restrict__ noise,
    float* __restrict__ out, const int* __restrict__ flag_cnt,
    const int* __restrict__ flag_list)
{
    __shared__ double red[8][64];   // [quarter*2 + mat][expert]
    const int tid = threadIdx.x;
    const int lane = tid & 63, wq = tid >> 6;
    int nf = *flag_cnt; if (nf > MAXFLAG) nf = MAXFLAG;
    for (int fi = blockIdx.x; fi < nf; fi += gridDim.x) {
        const int gt = flag_list[fi];
        const float* xr = x + (size_t)gt * NE + wq * 1024;
        const float* wr = w_route + (size_t)wq * 1024 * NX;
        const float* wn = w_noise + (size_t)wq * 1024 * NX;
        double ar0 = 0, ar1 = 0, an0 = 0, an1 = 0;
        for (int k = 0; k < 1024; k += 2) {
            double x0 = xr[k], x1 = xr[k + 1];
            ar0 += x0 * (double)wr[(size_t)k * NX + lane];
            ar1 += x1 * (double)wr[(size_t)(k + 1) * NX + lane];
            an0 += x0 * (double)wn[(size_t)k * NX + lane];
            an1 += x1 * (double)wn[(size_t)(k + 1) * NX + lane];
        }
        red[wq * 2][lane]     = ar0 + ar1;
        red[wq * 2 + 1][lane] = an0 + an1;
        __syncthreads();
        if (tid < 64) {
            double lr = red[0][lane] + red[2][lane] + red[4][lane] + red[6][lane]
                      + (double)b_route[lane];
            double ln = red[1][lane] + red[3][lane] + red[5][lane] + red[7][lane]
                      + (double)b_noise[lane];
            double nz = (double)noise[(size_t)gt * NX + lane];
            double sp = (ln > 0.0) ? (ln + log1p(exp(-ln))) : log1p(exp(ln));
            double v  = lr + nz * sp;
            double vv = v;
            double tv[8]; int ti[8];
            #pragma unroll
            for (int s = 0; s < 8; ++s) {
                double mv = vv; int mi = lane;
                #pragma unroll
                for (int off = 32; off > 0; off >>= 1) {
                    double ov = __shfl_xor(mv, off);
                    int    oi = __shfl_xor(mi, off);
                    if (ov > mv || (ov == mv && oi < mi)) { mv = ov; mi = oi; }
                }
                tv[s] = mv; ti[s] = mi;
                if (lane == mi) vv = -1.0e300;
            }
            double m0 = tv[0], s8 = 0.0, e8[8];
            #pragma unroll
            for (int s = 0; s < 8; ++s) { e8[s] = exp(tv[s] - m0); s8 += e8[s]; }
            float r = 0.f;
            #pragma unroll
            for (int s = 0; s < 8; ++s) if (ti[s] == lane) r = (float)(e8[s] / s8);
            out[(size_t)gt * NX + lane] = r;
            if (lane < TK) out[TI_OFF + (size_t)gt * TK + lane] = (float)ti[lane];
        }
        __syncthreads();
    }
}

// ---------------------------------------------------------------------------
__global__ __launch_bounds__(64) void finalize_kernel(
    const float* __restrict__ ps_acc, const float* __restrict__ fr_acc,
    const float* __restrict__ lse2_acc, float* __restrict__ out)
{
    const int lane = threadIdx.x;
    float p = ps_acc[lane], f = fr_acc[lane];
    float sp = p, sf = f;
    #pragma unroll
    for (int off = 32; off > 0; off >>= 1) {
        sp += __shfl_xor(sp, off);
        sf += __shfl_xor(sf, off);
    }
    float d = (p / fmaxf(sp, 1e-12f)) * (f / fmaxf(sf, 1e-12f));
    #pragma unroll
    for (int off = 32; off > 0; off >>= 1) d += __shfl_xor(d, off);
    if (lane == 0)
        out[AUX_IDX] = 64.f * d + 0.1f * (lse2_acc[0] / (float)NT);
}

// ---------------------------------------------------------------------------
extern "C" void kernel_launch(void* const* d_in, const int* in_sizes, int n_in,
                              void* d_out, int out_size, void* d_ws, size_t ws_size,
                              hipStream_t stream) {
    const float* x       = (const float*)d_in[0];
    const float* w_route = (const float*)d_in[1];
    const float* b_route = (const float*)d_in[2];
    const float* w_noise = (const float*)d_in[3];
    const float* b_noise = (const float*)d_in[4];
    const float* noise   = (const float*)d_in[5];
    float* out = (float*)d_out;

    float* ps   = (float*)d_ws;          // [64]
    float* fr   = ps + 64;               // [64]
    float* lse2 = ps + 128;              // [1]
    int* flag_cnt  = (int*)(ps + 129);   // [1]
    int* flag_list = (int*)(ps + 130);   // [MAXFLAG]

    hipMemsetAsync(d_ws, 0, (size_t)STATS_FLOATS * sizeof(float), stream);

    if (ws_size >= WS_NEED) {
        unsigned short* wt_hi = (unsigned short*)((char*)d_ws + WPACK_OFF);
        unsigned short* wt_lo = wt_hi + WMAT_ELEMS;
        prep_w_kernel<<<64, 256, 0, stream>>>(w_route, w_noise, wt_hi, wt_lo);
        fused_router_mfma<<<NT / BM, 256, 0, stream>>>(
            x, wt_hi, wt_lo, b_route, b_noise, noise, out,
            ps, fr, lse2, flag_cnt, flag_list);
    } else {
        fused_router_kernel<<<NT / BM, 256, 0, stream>>>(
            x, w_route, b_route, w_noise, b_noise, noise, out,
            ps, fr, lse2, flag_cnt, flag_list);
    }

    refine_kernel<<<1024, 256, 0, stream>>>(
        x, w_route, b_route, w_noise, b_noise, noise, out, flag_cnt, flag_list);

    finalize_kernel<<<1, 64, 0, stream>>>(ps, fr, lse2, out);
}

// Round 3
// 252.136 us; speedup vs baseline: 2.5043x; 1.2703x over previous
//
#include <hip/hip_runtime.h>
#include <math.h>

#define NT 16384     // tokens
#define NE 4096      // embed
#define NX 64        // experts
#define TK 8         // top-k

// split-K MFMA GEMM tiling
#define BM 128
#define BN 128
#define BK 32
#define KSPLIT 4
#define KTB (NE / KSPLIT / BK)   // 32 k-tiles per block
#define NMT (NT / BM)            // 128 m-tiles

#define RO_SIZE (NT * NX)
#define TI_OFF  RO_SIZE
#define AUX_IDX (RO_SIZE + NT * TK)

#define MAXFLAG 8192
#define STATS_FLOATS (130 + MAXFLAG)
#define WPACK_OFF ((((STATS_FLOATS * 4) + 255) / 256) * 256)
#define WMAT_ELEMS (128 * NE)                        // bf16 per packed matrix
#define PART_OFF (WPACK_OFF + 2 * WMAT_ELEMS * 2)    // after wt_hi+wt_lo (2 MB)
#define PART_FLOATS ((size_t)NMT * KSPLIT * BM * BN) // 32 MB / 4
#define WS_NEED_FULL ((size_t)PART_OFF + PART_FLOATS * 4)
#define WS_NEED_MID  ((size_t)WPACK_OFF + 2 * (size_t)WMAT_ELEMS * 2)

#define DELTA_FP32 5e-5f
#define DELTA_BF16 2.5e-4f

typedef __attribute__((ext_vector_type(8))) short bf16x8_t;
typedef __attribute__((ext_vector_type(4))) float f32x4_t;

__device__ __forceinline__ float neginf() { return __int_as_float(0xff800000); }

__device__ __forceinline__ unsigned short bf16_trunc(float f) {
    return (unsigned short)(__float_as_uint(f) >> 16);
}
__device__ __forceinline__ unsigned short bf16_rtn(float f) {
    unsigned u = __float_as_uint(f);
    unsigned r = u + 0x7fffu + ((u >> 16) & 1u);
    return (unsigned short)(r >> 16);
}
__device__ __forceinline__ float bf16_to_f(unsigned short h) {
    return __uint_as_float(((unsigned)h) << 16);
}

// ---------------------------------------------------------------------------
// prep: w_route|w_noise fp32 [4096][64] -> wt_hi/wt_lo bf16 [128 cols][4096 k]
// ---------------------------------------------------------------------------
__global__ __launch_bounds__(256) void prep_w_kernel(
    const float* __restrict__ w_route, const float* __restrict__ w_noise,
    unsigned short* __restrict__ wt_hi, unsigned short* __restrict__ wt_lo)
{
    __shared__ unsigned short hi[128][64];
    __shared__ unsigned short lo[128][64];
    const int t = threadIdx.x;
    const int k0 = blockIdx.x * 64;

    #pragma unroll
    for (int s = 0; s < 4; ++s) {
        int f = t + s * 256;
        int kr = f >> 4;
        int e4 = (f & 15) * 4;
        float4 vr = *(const float4*)(w_route + (size_t)(k0 + kr) * NX + e4);
        float4 vn = *(const float4*)(w_noise + (size_t)(k0 + kr) * NX + e4);
        float ar[4] = {vr.x, vr.y, vr.z, vr.w};
        float an[4] = {vn.x, vn.y, vn.z, vn.w};
        #pragma unroll
        for (int j = 0; j < 4; ++j) {
            unsigned short h = bf16_trunc(ar[j]);
            hi[e4 + j][kr] = h;
            lo[e4 + j][kr] = bf16_rtn(ar[j] - bf16_to_f(h));
            h = bf16_trunc(an[j]);
            hi[64 + e4 + j][kr] = h;
            lo[64 + e4 + j][kr] = bf16_rtn(an[j] - bf16_to_f(h));
        }
    }
    __syncthreads();
    #pragma unroll
    for (int s = 0; s < 4; ++s) {
        int c = t + s * 256;
        int col = c >> 3;
        int ks = (c & 7) * 8;
        *(bf16x8_t*)(wt_hi + (size_t)col * NE + k0 + ks) = *(bf16x8_t*)&hi[col][ks];
        *(bf16x8_t*)(wt_lo + (size_t)col * NE + k0 + ks) = *(bf16x8_t*)&lo[col][ks];
    }
}

// ---------------------------------------------------------------------------
// split-K bf16x3 MFMA GEMM: grid 512 (mtile*4+ks), 512 threads (8 waves)
// writes partial[mtile][ks][128][128] fp32
// ---------------------------------------------------------------------------
__global__ __launch_bounds__(512) void gemm_splitk_kernel(
    const float* __restrict__ x,
    const unsigned short* __restrict__ wt_hi,
    const unsigned short* __restrict__ wt_lo,
    float* __restrict__ partial)
{
    // per buffer (ushort): A_hi[0,4096) A_lo[4096,8192) B_hi[8192,12288) B_lo[12288,16384)
    __shared__ __align__(16) unsigned short lds[2][16384];   // 64 KB

    const int tid = threadIdx.x;
    const int mtile = blockIdx.x >> 2;
    const int ks = blockIdx.x & 3;
    const int bm = mtile * BM;
    const int kbase = ks * (NE / KSPLIT);

    const int wid = tid >> 6;
    const int lane = tid & 63;
    const int l15 = lane & 15;
    const int kg = lane >> 4;
    const int wr0 = (wid >> 1) * 32;
    const int wc0 = (wid & 1) * 64;

    const int arow = tid >> 2, asl = tid & 3;    // A: 128 rows x 4 slots(8 floats)
    const int bcol = tid >> 2, bsl = tid & 3;    // B: 128 cols x 4 slots(8 bf16)

    f32x4_t acc[2][4];
    #pragma unroll
    for (int rf = 0; rf < 2; ++rf)
        #pragma unroll
        for (int cf = 0; cf < 4; ++cf)
            acc[rf][cf] = (f32x4_t){0.f, 0.f, 0.f, 0.f};

    float4 pa0, pa1;
    bf16x8_t pbh, pbl;

    #define LOAD_TILE(TKI) do {                                                  \
        const int k0_ = kbase + (TKI) * BK;                                      \
        const float* xp_ = x + (size_t)(bm + arow) * NE + k0_ + asl * 8;         \
        pa0 = *(const float4*)xp_;                                               \
        pa1 = *(const float4*)(xp_ + 4);                                         \
        pbh = *(const bf16x8_t*)(wt_hi + (size_t)bcol * NE + k0_ + bsl * 8);     \
        pbl = *(const bf16x8_t*)(wt_lo + (size_t)bcol * NE + k0_ + bsl * 8);     \
    } while (0)

    #define WRITE_TILE(BUF) do {                                                 \
        float af_[8] = {pa0.x, pa0.y, pa0.z, pa0.w, pa1.x, pa1.y, pa1.z, pa1.w}; \
        bf16x8_t hv_, lv_;                                                       \
        _Pragma("unroll")                                                        \
        for (int j = 0; j < 8; ++j) {                                            \
            unsigned short h_ = bf16_trunc(af_[j]);                              \
            hv_[j] = (short)h_;                                                  \
            lv_[j] = (short)bf16_rtn(af_[j] - bf16_to_f(h_));                    \
        }                                                                        \
        int pa_ = asl ^ ((arow >> 1) & 3);                                       \
        *(bf16x8_t*)&lds[BUF][arow * 32 + pa_ * 8]        = hv_;                 \
        *(bf16x8_t*)&lds[BUF][4096 + arow * 32 + pa_ * 8] = lv_;                 \
        int pb_ = bsl ^ ((bcol >> 1) & 3);                                       \
        *(bf16x8_t*)&lds[BUF][8192  + bcol * 32 + pb_ * 8] = pbh;                \
        *(bf16x8_t*)&lds[BUF][12288 + bcol * 32 + pb_ * 8] = pbl;                \
    } while (0)

    LOAD_TILE(0);
    WRITE_TILE(0);
    __syncthreads();

    for (int tk = 0; tk < KTB; ++tk) {
        const int cur = tk & 1;
        if (tk + 1 < KTB) LOAD_TILE(tk + 1);

        {
            const unsigned short* Ah = &lds[cur][0];
            const unsigned short* Al = &lds[cur][4096];
            const unsigned short* Bh = &lds[cur][8192];
            const unsigned short* Bl = &lds[cur][12288];
            bf16x8_t ah[2], al[2], bh[4], bl[4];
            #pragma unroll
            for (int rf = 0; rf < 2; ++rf) {
                int row = wr0 + rf * 16 + l15;
                int off = row * 32 + ((kg ^ ((row >> 1) & 3)) << 3);
                ah[rf] = *(const bf16x8_t*)(Ah + off);
                al[rf] = *(const bf16x8_t*)(Al + off);
            }
            #pragma unroll
            for (int cf = 0; cf < 4; ++cf) {
                int col = wc0 + cf * 16 + l15;
                int off = col * 32 + ((kg ^ ((col >> 1) & 3)) << 3);
                bh[cf] = *(const bf16x8_t*)(Bh + off);
                bl[cf] = *(const bf16x8_t*)(Bl + off);
            }
            #pragma unroll
            for (int rf = 0; rf < 2; ++rf)
                #pragma unroll
                for (int cf = 0; cf < 4; ++cf) {
                    acc[rf][cf] = __builtin_amdgcn_mfma_f32_16x16x32_bf16(
                        ah[rf], bh[cf], acc[rf][cf], 0, 0, 0);
                    acc[rf][cf] = __builtin_amdgcn_mfma_f32_16x16x32_bf16(
                        ah[rf], bl[cf], acc[rf][cf], 0, 0, 0);
                    acc[rf][cf] = __builtin_amdgcn_mfma_f32_16x16x32_bf16(
                        al[rf], bh[cf], acc[rf][cf], 0, 0, 0);
                }
        }

        if (tk + 1 < KTB) WRITE_TILE(cur ^ 1);
        __syncthreads();
    }

    // write partial tile
    float* pb = partial + (size_t)blockIdx.x * (BM * BN);
    #pragma unroll
    for (int rf = 0; rf < 2; ++rf)
        #pragma unroll
        for (int cf = 0; cf < 4; ++cf)
            #pragma unroll
            for (int j = 0; j < 4; ++j) {
                int row = wr0 + rf * 16 + (lane >> 4) * 4 + j;
                int col = wc0 + cf * 16 + l15;
                pb[row * BN + col] = acc[rf][cf][j];
            }
    #undef LOAD_TILE
    #undef WRITE_TILE
}

// ---------------------------------------------------------------------------
// routing epilogue: grid 512 (mtile*4+quarter), 256 threads (4 waves x 8 tok)
// ---------------------------------------------------------------------------
__global__ __launch_bounds__(256) void routing_kernel(
    const float* __restrict__ partial,
    const float* __restrict__ b_route, const float* __restrict__ b_noise,
    const float* __restrict__ noise,
    float* __restrict__ out,
    float* __restrict__ ps_acc, float* __restrict__ fr_acc,
    float* __restrict__ lse2_acc,
    int* __restrict__ flag_cnt, int* __restrict__ flag_list)
{
    const int tid = threadIdx.x;
    const int mtile = blockIdx.x >> 2;
    const int qr = blockIdx.x & 3;
    const int wid = tid >> 6;
    const int lane = tid & 63;

    const float br = b_route[lane];
    const float bnv = b_noise[lane];
    float ps_l = 0.f, fr_l = 0.f, l2_l = 0.f;

    for (int tt = 0; tt < 8; ++tt) {
        const int tok = qr * 32 + wid * 8 + tt;      // 0..127 within tile
        const int gt  = mtile * BM + tok;
        float lr = br, ln = bnv;
        #pragma unroll
        for (int ks = 0; ks < KSPLIT; ++ks) {
            const float* pb = partial + ((size_t)(mtile * KSPLIT + ks)) * (BM * BN)
                            + tok * BN;
            lr += pb[lane];
            ln += pb[64 + lane];
        }
        float nz = noise[(size_t)gt * NX + lane];
        float sp = fmaxf(ln, 0.f) + log1pf(expf(-fabsf(ln)));   // softplus
        float v  = lr + nz * sp;                                 // noisy logit

        // top-9 iterative wave argmax (ties -> lower index)
        float vv = v;
        float tv[9]; int ti[9];
        #pragma unroll
        for (int s = 0; s < 9; ++s) {
            float mv = vv; int mi = lane;
            #pragma unroll
            for (int off = 32; off > 0; off >>= 1) {
                float ov = __shfl_xor(mv, off);
                int   oi = __shfl_xor(mi, off);
                if (ov > mv || (ov == mv && oi < mi)) { mv = ov; mi = oi; }
            }
            tv[s] = mv; ti[s] = mi;
            if (lane == mi) vv = neginf();
        }

        float ming = 1e30f;
        #pragma unroll
        for (int s = 0; s < 8; ++s) ming = fminf(ming, tv[s] - tv[s + 1]);
        if (lane == 0 && ming < DELTA_BF16) {
            int p = atomicAdd(flag_cnt, 1);
            if (p < MAXFLAG) flag_list[p] = gt;
        }

        const float m0 = tv[0];
        float e8[8], s8 = 0.f;
        #pragma unroll
        for (int s = 0; s < 8; ++s) { e8[s] = expf(tv[s] - m0); s8 += e8[s]; }
        float r = 0.f;
        #pragma unroll
        for (int s = 0; s < 8; ++s) if (ti[s] == lane) r = e8[s] / s8;
        out[(size_t)gt * NX + lane] = r;
        if (lane < TK) out[TI_OFF + (size_t)gt * TK + lane] = (float)ti[lane];

        float p = expf(v - m0);
        float s64 = p;
        #pragma unroll
        for (int off = 32; off > 0; off >>= 1) s64 += __shfl_xor(s64, off);
        ps_l += p / s64;
        if (lane == 0) { float lse = m0 + logf(s64); l2_l += lse * lse; }

        unsigned tm8 = 0;
        #pragma unroll
        for (int s = 0; s < 8; ++s) if (ti[s] < TK) tm8 |= (1u << ti[s]);
        #pragma unroll
        for (int s = 0; s < 8; ++s)
            if (ti[s] == lane && ((tm8 >> s) & 1u)) fr_l += 1.f;
    }
    atomicAdd(&ps_acc[lane], ps_l);
    atomicAdd(&fr_acc[lane], fr_l);
    if (lane == 0) atomicAdd(lse2_acc, l2_l);
}

// ---------------------------------------------------------------------------
// Fallback fp32-VALU fused kernel (round-1 verified) for small ws_size
// ---------------------------------------------------------------------------
#define FBM 64
#define FBN 128
#define FBK 32
#define XPITCH (FBM + 4)
__global__ __launch_bounds__(256) void fused_router_kernel(
    const float* __restrict__ x,
    const float* __restrict__ w_route, const float* __restrict__ b_route,
    const float* __restrict__ w_noise, const float* __restrict__ b_noise,
    const float* __restrict__ noise,
    float* __restrict__ out,
    float* __restrict__ ps_acc, float* __restrict__ fr_acc,
    float* __restrict__ lse2_acc,
    int* __restrict__ flag_cnt, int* __restrict__ flag_list)
{
    __shared__ float smem[FBM * FBN];
    float* xs  = smem;
    float* wst = smem + FBK * XPITCH;
    const int tid = threadIdx.x;
    const int block_m = blockIdx.x * FBM;
    const int row0 = (tid >> 5) * 8;
    const int col0 = (tid & 31) * 4;
    float acc[8][4];
    #pragma unroll
    for (int i = 0; i < 8; ++i)
        #pragma unroll
        for (int j = 0; j < 4; ++j) acc[i][j] = 0.f;
    float4 px[2], pw[4];
    {
        #pragma unroll
        for (int s = 0; s < 2; ++s) {
            int f = tid + s * 256, r = f >> 3, kq = f & 7;
            px[s] = *reinterpret_cast<const float4*>(x + (size_t)(block_m + r) * NE + kq * 4);
        }
        #pragma unroll
        for (int s = 0; s < 4; ++s) {
            int f = tid + s * 256, kk = f >> 5, c4 = (f & 31) * 4;
            const float* src = (c4 < NX) ? (w_route + (size_t)kk * NX + c4)
                                         : (w_noise + (size_t)kk * NX + (c4 - NX));
            pw[s] = *reinterpret_cast<const float4*>(src);
        }
    }
    for (int t = 0; t < NE / FBK; ++t) {
        __syncthreads();
        #pragma unroll
        for (int s = 0; s < 2; ++s) {
            int f = tid + s * 256, r = f >> 3, kq = f & 7;
            xs[(kq * 4 + 0) * XPITCH + r] = px[s].x;
            xs[(kq * 4 + 1) * XPITCH + r] = px[s].y;
            xs[(kq * 4 + 2) * XPITCH + r] = px[s].z;
            xs[(kq * 4 + 3) * XPITCH + r] = px[s].w;
        }
        #pragma unroll
        for (int s = 0; s < 4; ++s) {
            int f = tid + s * 256, kk = f >> 5, c4 = (f & 31) * 4;
            *reinterpret_cast<float4*>(&wst[kk * FBN + c4]) = pw[s];
        }
        __syncthreads();
        if (t + 1 < NE / FBK) {
            const int k0 = (t + 1) * FBK;
            #pragma unroll
            for (int s = 0; s < 2; ++s) {
                int f = tid + s * 256, r = f >> 3, kq = f & 7;
                px[s] = *reinterpret_cast<const float4*>(x + (size_t)(block_m + r) * NE + k0 + kq * 4);
            }
            #pragma unroll
            for (int s = 0; s < 4; ++s) {
                int f = tid + s * 256, kk = f >> 5, c4 = (f & 31) * 4;
                const float* src = (c4 < NX) ? (w_route + (size_t)(k0 + kk) * NX + c4)
                                             : (w_noise + (size_t)(k0 + kk) * NX + (c4 - NX));
                pw[s] = *reinterpret_cast<const float4*>(src);
            }
        }
        #pragma unroll
        for (int k = 0; k < FBK; ++k) {
            float4 xa = *reinterpret_cast<const float4*>(&xs[k * XPITCH + row0]);
            float4 xb = *reinterpret_cast<const float4*>(&xs[k * XPITCH + row0 + 4]);
            float4 wv = *reinterpret_cast<const float4*>(&wst[k * FBN + col0]);
            float xf[8] = {xa.x, xa.y, xa.z, xa.w, xb.x, xb.y, xb.z, xb.w};
            float wf[4] = {wv.x, wv.y, wv.z, wv.w};
            #pragma unroll
            for (int i = 0; i < 8; ++i)
                #pragma unroll
                for (int j = 0; j < 4; ++j)
                    acc[i][j] = fmaf(xf[i], wf[j], acc[i][j]);
        }
    }
    __syncthreads();
    #pragma unroll
    for (int i = 0; i < 8; ++i) {
        float4 v = make_float4(acc[i][0], acc[i][1], acc[i][2], acc[i][3]);
        *reinterpret_cast<float4*>(&smem[(row0 + i) * FBN + col0]) = v;
    }
    __syncthreads();
    const int wave = tid >> 6;
    const int lane = tid & 63;
    const float br = b_route[lane];
    const float bnv = b_noise[lane];
    float ps_l = 0.f, fr_l = 0.f, l2_l = 0.f;
    for (int tt = 0; tt < FBM / 4; ++tt) {
        const int tok = wave * (FBM / 4) + tt;
        const int gt  = block_m + tok;
        float lr = smem[tok * FBN + lane] + br;
        float ln = smem[tok * FBN + NX + lane] + bnv;
        float nz = noise[(size_t)gt * NX + lane];
        float sp = fmaxf(ln, 0.f) + log1pf(expf(-fabsf(ln)));
        float v  = lr + nz * sp;
        float vv = v;
        float tv[9]; int ti[9];
        #pragma unroll
        for (int s = 0; s < 9; ++s) {
            float mv = vv; int mi = lane;
            #pragma unroll
            for (int off = 32; off > 0; off >>= 1) {
                float ov = __shfl_xor(mv, off);
                int   oi = __shfl_xor(mi, off);
                if (ov > mv || (ov == mv && oi < mi)) { mv = ov; mi = oi; }
            }
            tv[s] = mv; ti[s] = mi;
            if (lane == mi) vv = neginf();
        }
        float ming = 1e30f;
        #pragma unroll
        for (int s = 0; s < 8; ++s) ming = fminf(ming, tv[s] - tv[s + 1]);
        if (lane == 0 && ming < DELTA_FP32) {
            int p = atomicAdd(flag_cnt, 1);
            if (p < MAXFLAG) flag_list[p] = gt;
        }
        const float m0 = tv[0];
        float e8[8], s8 = 0.f;
        #pragma unroll
        for (int s = 0; s < 8; ++s) { e8[s] = expf(tv[s] - m0); s8 += e8[s]; }
        float r = 0.f;
        #pragma unroll
        for (int s = 0; s < 8; ++s) if (ti[s] == lane) r = e8[s] / s8;
        out[(size_t)gt * NX + lane] = r;
        if (lane < TK) out[TI_OFF + (size_t)gt * TK + lane] = (float)ti[lane];
        float p = expf(v - m0);
        float s64 = p;
        #pragma unroll
        for (int off = 32; off > 0; off >>= 1) s64 += __shfl_xor(s64, off);
        ps_l += p / s64;
        if (lane == 0) { float lse = m0 + logf(s64); l2_l += lse * lse; }
        unsigned tm8 = 0;
        #pragma unroll
        for (int s = 0; s < 8; ++s) if (ti[s] < TK) tm8 |= (1u << ti[s]);
        #pragma unroll
        for (int s = 0; s < 8; ++s)
            if (ti[s] == lane && ((tm8 >> s) & 1u)) fr_l += 1.f;
    }
    atomicAdd(&ps_acc[lane], ps_l);
    atomicAdd(&fr_acc[lane], fr_l);
    if (lane == 0) atomicAdd(lse2_acc, l2_l);
}

// ---------------------------------------------------------------------------
// fp64 repair of near-tie tokens
// ---------------------------------------------------------------------------
__global__ __launch_bounds__(256) void refine_kernel(
    const float* __restrict__ x, const float* __restrict__ w_route,
    const float* __restrict__ b_route, const float* __restrict__ w_noise,
    const float* __restrict__ b_noise, const float* __restrict__ noise,
    float* __restrict__ out, const int* __restrict__ flag_cnt,
    const int* __restrict__ flag_list)
{
    __shared__ double red[8][64];
    const int tid = threadIdx.x;
    const int lane = tid & 63, wq = tid >> 6;
    int nf = *flag_cnt; if (nf > MAXFLAG) nf = MAXFLAG;
    for (int fi = blockIdx.x; fi < nf; fi += gridDim.x) {
        const int gt = flag_list[fi];
        const float* xr = x + (size_t)gt * NE + wq * 1024;
        const float* wr = w_route + (size_t)wq * 1024 * NX;
        const float* wn = w_noise + (size_t)wq * 1024 * NX;
        double ar0 = 0, ar1 = 0, an0 = 0, an1 = 0;
        for (int k = 0; k < 1024; k += 2) {
            double x0 = xr[k], x1 = xr[k + 1];
            ar0 += x0 * (double)wr[(size_t)k * NX + lane];
            ar1 += x1 * (double)wr[(size_t)(k + 1) * NX + lane];
            an0 += x0 * (double)wn[(size_t)k * NX + lane];
            an1 += x1 * (double)wn[(size_t)(k + 1) * NX + lane];
        }
        red[wq * 2][lane]     = ar0 + ar1;
        red[wq * 2 + 1][lane] = an0 + an1;
        __syncthreads();
        if (tid < 64) {
            double lr = red[0][lane] + red[2][lane] + red[4][lane] + red[6][lane]
                      + (double)b_route[lane];
            double ln = red[1][lane] + red[3][lane] + red[5][lane] + red[7][lane]
                      + (double)b_noise[lane];
            double nz = (double)noise[(size_t)gt * NX + lane];
            double sp = (ln > 0.0) ? (ln + log1p(exp(-ln))) : log1p(exp(ln));
            double v  = lr + nz * sp;
            double vv = v;
            double tv[8]; int ti[8];
            #pragma unroll
            for (int s = 0; s < 8; ++s) {
                double mv = vv; int mi = lane;
                #pragma unroll
                for (int off = 32; off > 0; off >>= 1) {
                    double ov = __shfl_xor(mv, off);
                    int    oi = __shfl_xor(mi, off);
                    if (ov > mv || (ov == mv && oi < mi)) { mv = ov; mi = oi; }
                }
                tv[s] = mv; ti[s] = mi;
                if (lane == mi) vv = -1.0e300;
            }
            double m0 = tv[0], s8 = 0.0, e8[8];
            #pragma unroll
            for (int s = 0; s < 8; ++s) { e8[s] = exp(tv[s] - m0); s8 += e8[s]; }
            float r = 0.f;
            #pragma unroll
            for (int s = 0; s < 8; ++s) if (ti[s] == lane) r = (float)(e8[s] / s8);
            out[(size_t)gt * NX + lane] = r;
            if (lane < TK) out[TI_OFF + (size_t)gt * TK + lane] = (float)ti[lane];
        }
        __syncthreads();
    }
}

// ---------------------------------------------------------------------------
__global__ __launch_bounds__(64) void finalize_kernel(
    const float* __restrict__ ps_acc, const float* __restrict__ fr_acc,
    const float* __restrict__ lse2_acc, float* __restrict__ out)
{
    const int lane = threadIdx.x;
    float p = ps_acc[lane], f = fr_acc[lane];
    float sp = p, sf = f;
    #pragma unroll
    for (int off = 32; off > 0; off >>= 1) {
        sp += __shfl_xor(sp, off);
        sf += __shfl_xor(sf, off);
    }
    float d = (p / fmaxf(sp, 1e-12f)) * (f / fmaxf(sf, 1e-12f));
    #pragma unroll
    for (int off = 32; off > 0; off >>= 1) d += __shfl_xor(d, off);
    if (lane == 0)
        out[AUX_IDX] = 64.f * d + 0.1f * (lse2_acc[0] / (float)NT);
}

// ---------------------------------------------------------------------------
extern "C" void kernel_launch(void* const* d_in, const int* in_sizes, int n_in,
                              void* d_out, int out_size, void* d_ws, size_t ws_size,
                              hipStream_t stream) {
    const float* x       = (const float*)d_in[0];
    const float* w_route = (const float*)d_in[1];
    const float* b_route = (const float*)d_in[2];
    const float* w_noise = (const float*)d_in[3];
    const float* b_noise = (const float*)d_in[4];
    const float* noise   = (const float*)d_in[5];
    float* out = (float*)d_out;

    float* ps   = (float*)d_ws;
    float* fr   = ps + 64;
    float* lse2 = ps + 128;
    int* flag_cnt  = (int*)(ps + 129);
    int* flag_list = (int*)(ps + 130);

    hipMemsetAsync(d_ws, 0, (size_t)STATS_FLOATS * sizeof(float), stream);

    if (ws_size >= WS_NEED_FULL) {
        unsigned short* wt_hi = (unsigned short*)((char*)d_ws + WPACK_OFF);
        unsigned short* wt_lo = wt_hi + WMAT_ELEMS;
        float* part = (float*)((char*)d_ws + PART_OFF);
        prep_w_kernel<<<64, 256, 0, stream>>>(w_route, w_noise, wt_hi, wt_lo);
        gemm_splitk_kernel<<<NMT * KSPLIT, 512, 0, stream>>>(x, wt_hi, wt_lo, part);
        routing_kernel<<<NMT * 4, 256, 0, stream>>>(
            part, b_route, b_noise, noise, out, ps, fr, lse2, flag_cnt, flag_list);
    } else {
        fused_router_kernel<<<NT / FBM, 256, 0, stream>>>(
            x, w_route, b_route, w_noise, b_noise, noise, out,
            ps, fr, lse2, flag_cnt, flag_list);
    }

    refine_kernel<<<1024, 256, 0, stream>>>(
        x, w_route, b_route, w_noise, b_noise, noise, out, flag_cnt, flag_list);

    finalize_kernel<<<1, 64, 0, stream>>>(ps, fr, lse2, out);
}